// Round 2
// baseline (225.890 us; speedup 1.0000x reference)
//
#include <hip/hip_runtime.h>
#include <math.h>

#define BB 32
#define TT 4096
#define FF 256
#define CH 64              // timesteps per K1 block
#define NC (TT / CH)       // 64 chunks per batch
#define K_TOP 409          // int(4096 * 0.1)
#define EMPH_HALF 0.5f     // (1.5 - 1.0)
#define NSEG 32            // combine segments per batch (128 timesteps each)
#define SEGT (TT / NSEG)   // 128
#define CPS (NC / NSEG)    // 2 chunks per segment

__device__ __forceinline__ unsigned flip_key(float v) {
    unsigned u = __float_as_uint(v);
    return (u & 0x80000000u) ? ~u : (u | 0x80000000u);
}
// fast tanh: (e^{2z}-1)/(e^{2z}+1), clamped so e^{2z} never overflows
__device__ __forceinline__ float fast_tanh(float z) {
    z = fminf(fmaxf(z, -15.f), 15.f);
    const float t = __expf(2.f * z);
    return (t - 1.f) * __builtin_amdgcn_rcpf(t + 1.f);
}

// ---------------------------------------------------------------------------
// K1: fused scores + online-softmax chunk partials. ONE HBM pass over x.
// grid = B*NC blocks of 256 (4 waves). Each wave owns 4 rows per 16-row
// sub-tile with a PRIVATE online-softmax state (no inner syncs); the 4
// wave-partials merge once at the end.
// Outputs: e[B*T], P[B*NC*F] = sum_t exp(e-m_c) x, cm[B*NC], cs[B*NC].
// Also zeros out[b,:] and kflag[b] (c==0 blocks) for the tail kernel.
// ---------------------------------------------------------------------------
__global__ __launch_bounds__(256) void fused_pass1(const float* __restrict__ x,
                                                   const float* __restrict__ W,
                                                   const float* __restrict__ bias,
                                                   float* __restrict__ e,
                                                   float* __restrict__ P,
                                                   float* __restrict__ cm,
                                                   float* __restrict__ cs,
                                                   unsigned* __restrict__ kflag,
                                                   float* __restrict__ out) {
    const int b = blockIdx.x / NC;
    const int c = blockIdx.x % NC;
    const int tid = threadIdx.x;
    const int wv = tid >> 6, ln = tid & 63;

    if (c == 0) {
        out[b * FF + tid] = 0.f;                // zero for tail's atomicAdd
        if (tid == 0) kflag[b] = 0u;            // spin-flag sentinel
    }

    const float* xc = x + ((size_t)b * TT + (size_t)c * CH) * FF;
    const float4 wvec = ((const float4*)W)[ln];
    const float  bb   = bias[0];

    float4 acc = make_float4(0.f, 0.f, 0.f, 0.f);
    float  m = -1e30f, ssum = 0.f;

    #pragma unroll
    for (int s0 = 0; s0 < CH; s0 += 16) {
        const int r0 = s0 + wv * 4;             // this wave's 4 rows
        float4 xr[4];
        #pragma unroll
        for (int i = 0; i < 4; i++)
            xr[i] = ((const float4*)(xc + (size_t)(r0 + i) * FF))[ln];

        float dv[4];
        #pragma unroll
        for (int i = 0; i < 4; i++)
            dv[i] = xr[i].x * wvec.x + xr[i].y * wvec.y +
                    xr[i].z * wvec.z + xr[i].w * wvec.w;
        #pragma unroll
        for (int i = 0; i < 4; i++) {
            float d = dv[i];
            #pragma unroll
            for (int off = 32; off; off >>= 1) d += __shfl_xor(d, off);
            dv[i] = fast_tanh(d + bb);          // all 64 lanes hold the score
        }
        if (ln == 0)
            *(float4*)(e + (size_t)b * TT + c * CH + r0) =
                make_float4(dv[0], dv[1], dv[2], dv[3]);

        // private online-softmax update (registers only, no sync)
        float lm = m;
        #pragma unroll
        for (int i = 0; i < 4; i++) lm = fmaxf(lm, dv[i]);
        const float alpha = __expf(m - lm);
        acc.x *= alpha; acc.y *= alpha; acc.z *= alpha; acc.w *= alpha;
        ssum *= alpha;
        #pragma unroll
        for (int i = 0; i < 4; i++) {
            const float wgt = __expf(dv[i] - lm);
            ssum += wgt;
            acc.x += wgt * xr[i].x; acc.y += wgt * xr[i].y;
            acc.z += wgt * xr[i].z; acc.w += wgt * xr[i].w;
        }
        m = lm;
    }

    // ---- merge the 4 per-wave partials (single sync) ----
    __shared__ float4 part4[4][64];
    __shared__ float sm[4], ss4[4];
    part4[wv][ln] = acc;
    if (ln == 0) { sm[wv] = m; ss4[wv] = ssum; }
    __syncthreads();

    const float m0 = sm[0], m1 = sm[1], m2 = sm[2], m3 = sm[3];
    const float mc = fmaxf(fmaxf(m0, m1), fmaxf(m2, m3));
    const float s0s = __expf(m0 - mc), s1s = __expf(m1 - mc);
    const float s2s = __expf(m2 - mc), s3s = __expf(m3 - mc);
    const float* pf = (const float*)part4;      // [4][256] floats
    const float p = pf[tid] * s0s + pf[256 + tid] * s1s +
                    pf[512 + tid] * s2s + pf[768 + tid] * s3s;
    P[((size_t)b * NC + c) * FF + tid] = p;
    if (tid == 0) {
        cm[b * NC + c] = mc;
        cs[b * NC + c] = ss4[0] * s0s + ss4[1] * s1s + ss4[2] * s2s + ss4[3] * s3s;
    }
}

// ---------------------------------------------------------------------------
// K2+K3 merged tail. grid = BB + BB*NSEG = 1056 blocks of 256.
// __launch_bounds__(256,5) guarantees >=5 blocks/CU -> 1280 slots >= 1056,
// so ALL blocks are co-resident and the per-batch spin-wait cannot deadlock.
//
// SELECT role (blockIdx < BB): single wave, 64 keys/lane, ballot-count radix
// select with ZERO barriers. Two early exits (tot==kk, ncand==kk) -- in both
// cases the zero-padded prefix is an exact threshold:
//   #{key >= prefix00..0} = (K_TOP - kk) + candidates = K_TOP.
// Publishes the threshold via kflag[b] (payload IS the flag; flip_key != 0).
//
// COMBINE role: computes gmax/Z locally from cm/cs (wave-reduce, no LDS),
// does the P-combine and the e-segment exp precompute BEFORE spinning on
// kflag[b] -- the whole select latency hides under this independent work.
// ---------------------------------------------------------------------------
__global__ __launch_bounds__(256, 5) void tail_kernel(const float* __restrict__ x,
                                                      const float* __restrict__ e,
                                                      const float* __restrict__ P,
                                                      const float* __restrict__ cm,
                                                      const float* __restrict__ cs,
                                                      unsigned* __restrict__ kflag,
                                                      float* __restrict__ out) {
    const int tid = threadIdx.x;

    if (blockIdx.x < BB) {
        // ---------------- SELECT role ----------------
        if (tid >= 64) return;                  // single wave, barrier-free
        const int b = blockIdx.x;
        const float4* eb4 = (const float4*)(e + (size_t)b * TT);
        unsigned key[64];
        #pragma unroll
        for (int j = 0; j < 16; j++) {
            const float4 v = eb4[j * 64 + tid];
            key[4 * j + 0] = flip_key(v.x);
            key[4 * j + 1] = flip_key(v.y);
            key[4 * j + 2] = flip_key(v.z);
            key[4 * j + 3] = flip_key(v.w);
        }
        unsigned prefix = 0u, mask = 0u;
        int kk = K_TOP, ncand = TT;
        for (int bit = 31; bit >= 0; bit--) {
            const unsigned bm = 1u << bit;
            const unsigned m2 = mask | bm;
            const unsigned want = prefix | bm;
            int cnt = 0;
            #pragma unroll
            for (int j = 0; j < 64; j++)
                cnt += (int)__popcll(__ballot((key[j] & m2) == want));
            if (cnt >= kk) {
                prefix = want;
                if (cnt == kk) break;           // exact: zero-padded prefix
                ncand = cnt;
            } else {
                kk -= cnt;
                ncand -= cnt;
                if (ncand == kk) break;         // all candidates are top-k
            }
            mask = m2;
        }
        if (tid == 0)
            __hip_atomic_store(kflag + b, prefix,
                               __ATOMIC_RELAXED, __HIP_MEMORY_SCOPE_AGENT);
        return;
    }

    // ---------------- COMBINE role ----------------
    const int cb = blockIdx.x - BB;
    const int b = cb / NSEG;
    const int s = cb % NSEG;
    const int ln = tid & 63;

    // gmax/Z from chunk stats, redundantly per wave (registers only)
    const float cmv = cm[b * NC + ln];
    const float csv = cs[b * NC + ln];
    float g = cmv;
    #pragma unroll
    for (int off = 32; off; off >>= 1) g = fmaxf(g, __shfl_xor(g, off));
    float zz = csv * __expf(cmv - g);
    #pragma unroll
    for (int off = 32; off; off >>= 1) zz += __shfl_xor(zz, off);

    // P-combine for this segment's chunks (cm via in-wave shuffle)
    float acc = 0.f;
    #pragma unroll
    for (int c = 0; c < CPS; c++) {
        const int cc = s * CPS + c;
        const float mcc = __shfl(cmv, cc);
        acc += P[((size_t)b * NC + cc) * FF + tid] * __expf(mcc - g);
    }

    // e-segment preload + emphasis weight precompute (threshold-independent)
    int t = 0; unsigned ky = 0u; float pv = 0.f;
    if (tid < SEGT) {
        t = s * SEGT + tid;
        const float ev = e[(size_t)b * TT + t];
        ky = flip_key(ev);
        pv = EMPH_HALF * __expf(ev - g);
    }

    __shared__ unsigned skey;
    __shared__ int scount;
    __shared__ int slist[SEGT];
    __shared__ float sval[SEGT];
    if (tid == 0) {
        scount = 0;
        unsigned k;
        do {
            k = __hip_atomic_load(kflag + b,
                                  __ATOMIC_RELAXED, __HIP_MEMORY_SCOPE_AGENT);
        } while (k == 0u);
        skey = k;
    }
    __syncthreads();
    const unsigned Kkey = skey;

    if (tid < SEGT && ky >= Kkey) {
        const int i = atomicAdd(&scount, 1);
        slist[i] = t;
        sval[i] = pv;
    }
    __syncthreads();

    const int n = scount;
    const float* xb = x + (size_t)b * TT * FF;
    int i = 0;
    for (; i + 4 <= n; i += 4) {
        const float* p0 = xb + (size_t)slist[i + 0] * FF;
        const float* p1 = xb + (size_t)slist[i + 1] * FF;
        const float* p2 = xb + (size_t)slist[i + 2] * FF;
        const float* p3 = xb + (size_t)slist[i + 3] * FF;
        const float w0 = sval[i + 0], w1 = sval[i + 1];
        const float w2 = sval[i + 2], w3 = sval[i + 3];
        acc += w0 * p0[tid] + w1 * p1[tid] + w2 * p2[tid] + w3 * p3[tid];
    }
    for (; i < n; i++)
        acc += sval[i] * xb[(size_t)slist[i] * FF + tid];

    atomicAdd(&out[b * FF + tid], acc * (1.f / zz));
}

// ---------------------------------------------------------------------------
extern "C" void kernel_launch(void* const* d_in, const int* in_sizes, int n_in,
                              void* d_out, int out_size, void* d_ws, size_t ws_size,
                              hipStream_t stream) {
    const float* x    = (const float*)d_in[0];   // [B,T,F]
    const float* W    = (const float*)d_in[1];   // [F,1]
    const float* bias = (const float*)d_in[2];   // [1]
    float* out = (float*)d_out;                  // [B,1,F]

    float* e     = (float*)d_ws;                 // B*T
    float* P     = e + (size_t)BB * TT;          // B*NC*F
    float* cm    = P + (size_t)BB * NC * FF;     // B*NC
    float* cs    = cm + BB * NC;                 // B*NC
    unsigned* kf = (unsigned*)(cs + BB * NC);    // B spin flags

    fused_pass1<<<BB * NC, 256, 0, stream>>>(x, W, bias, e, P, cm, cs, kf, out);
    tail_kernel<<<BB + BB * NSEG, 256, 0, stream>>>(x, e, P, cm, cs, kf, out);
}

// Round 3
// 210.417 us; speedup vs baseline: 1.0735x; 1.0735x over previous
//
#include <hip/hip_runtime.h>
#include <math.h>

#define BB 32
#define TT 4096
#define FF 256
#define CH 64              // timesteps per K1 block
#define NC (TT / CH)       // 64 chunks per batch
#define K_TOP 409          // int(4096 * 0.1)
#define EMPH_HALF 0.5f     // (1.5 - 1.0)
#define NSEG 32            // combine segments per batch (128 timesteps each)
#define SEGT (TT / NSEG)   // 128
#define CPS (NC / NSEG)    // 2 chunks per segment

__device__ __forceinline__ unsigned flip_key(float v) {
    unsigned u = __float_as_uint(v);
    return (u & 0x80000000u) ? ~u : (u | 0x80000000u);
}
// fast tanh: (e^{2z}-1)/(e^{2z}+1), clamped so e^{2z} never overflows
__device__ __forceinline__ float fast_tanh(float z) {
    z = fminf(fmaxf(z, -15.f), 15.f);
    const float t = __expf(2.f * z);
    return (t - 1.f) * __builtin_amdgcn_rcpf(t + 1.f);
}

// ---------------------------------------------------------------------------
// K1: fused scores + online-softmax chunk partials. ONE HBM pass over x.
// grid = B*NC blocks of 256 (4 waves). Each wave owns 4 rows per 16-row
// sub-tile with a PRIVATE online-softmax state (no inner syncs); the 4
// wave-partials merge once at the end.
// Outputs: e[B*T], P[B*NC*F] = sum_t exp(e-m_c) x, cm[B*NC], cs[B*NC].
// Also zeros out[b,:] (c==0 blocks) for K2's atomics.
// ---------------------------------------------------------------------------
__global__ __launch_bounds__(256) void fused_pass1(const float* __restrict__ x,
                                                   const float* __restrict__ W,
                                                   const float* __restrict__ bias,
                                                   float* __restrict__ e,
                                                   float* __restrict__ P,
                                                   float* __restrict__ cm,
                                                   float* __restrict__ cs,
                                                   float* __restrict__ out) {
    const int b = blockIdx.x / NC;
    const int c = blockIdx.x % NC;
    const int tid = threadIdx.x;
    const int wv = tid >> 6, ln = tid & 63;

    if (c == 0) out[b * FF + tid] = 0.f;        // zero for K2's atomicAdd

    const float* xc = x + ((size_t)b * TT + (size_t)c * CH) * FF;
    const float4 wvec = ((const float4*)W)[ln];
    const float  bb   = bias[0];

    float4 acc = make_float4(0.f, 0.f, 0.f, 0.f);
    float  m = -1e30f, ssum = 0.f;

    #pragma unroll
    for (int s0 = 0; s0 < CH; s0 += 16) {
        const int r0 = s0 + wv * 4;             // this wave's 4 rows
        float4 xr[4];
        #pragma unroll
        for (int i = 0; i < 4; i++)
            xr[i] = ((const float4*)(xc + (size_t)(r0 + i) * FF))[ln];

        float dv[4];
        #pragma unroll
        for (int i = 0; i < 4; i++)
            dv[i] = xr[i].x * wvec.x + xr[i].y * wvec.y +
                    xr[i].z * wvec.z + xr[i].w * wvec.w;
        #pragma unroll
        for (int i = 0; i < 4; i++) {
            float d = dv[i];
            #pragma unroll
            for (int off = 32; off; off >>= 1) d += __shfl_xor(d, off);
            dv[i] = fast_tanh(d + bb);          // all 64 lanes hold the score
        }
        if (ln == 0)
            *(float4*)(e + (size_t)b * TT + c * CH + r0) =
                make_float4(dv[0], dv[1], dv[2], dv[3]);

        // private online-softmax update (registers only, no sync)
        float lm = m;
        #pragma unroll
        for (int i = 0; i < 4; i++) lm = fmaxf(lm, dv[i]);
        const float alpha = __expf(m - lm);
        acc.x *= alpha; acc.y *= alpha; acc.z *= alpha; acc.w *= alpha;
        ssum *= alpha;
        #pragma unroll
        for (int i = 0; i < 4; i++) {
            const float wgt = __expf(dv[i] - lm);
            ssum += wgt;
            acc.x += wgt * xr[i].x; acc.y += wgt * xr[i].y;
            acc.z += wgt * xr[i].z; acc.w += wgt * xr[i].w;
        }
        m = lm;
    }

    // ---- merge the 4 per-wave partials (single sync) ----
    __shared__ float4 part4[4][64];
    __shared__ float sm[4], ss4[4];
    part4[wv][ln] = acc;
    if (ln == 0) { sm[wv] = m; ss4[wv] = ssum; }
    __syncthreads();

    const float m0 = sm[0], m1 = sm[1], m2 = sm[2], m3 = sm[3];
    const float mc = fmaxf(fmaxf(m0, m1), fmaxf(m2, m3));
    const float s0s = __expf(m0 - mc), s1s = __expf(m1 - mc);
    const float s2s = __expf(m2 - mc), s3s = __expf(m3 - mc);
    const float* pf = (const float*)part4;      // [4][256] floats
    const float p = pf[tid] * s0s + pf[256 + tid] * s1s +
                    pf[512 + tid] * s2s + pf[768 + tid] * s3s;
    P[((size_t)b * NC + c) * FF + tid] = p;
    if (tid == 0) {
        cm[b * NC + c] = mc;
        cs[b * NC + c] = ss4[0] * s0s + ss4[1] * s1s + ss4[2] * s2s + ss4[3] * s3s;
    }
}

// ---------------------------------------------------------------------------
// K2: combine + REDUNDANT in-block top-k select (no select kernel, no
// cross-kernel signaling). grid = B*NSEG = 1024 blocks of 256.
// Each block: gmax/Z from cm/cs (wave-reduce, registers), P-combine for its
// 2 chunks, then the verified 256-thread/16-key ballot radix select
// (1 barrier/round double-buffered, both early exits), then the top-k
// emphasis gather for its 128-timestep segment. The select is replicated
// 32x per batch but runs fully parallel -- it replaces a serial 32-block
// kernel plus a launch gap.
// out[b,f] += ( sum_c P*e^{m_c-gmax} + 0.5*sum_{topk t} e^{e_t-gmax} x ) / Z
// ---------------------------------------------------------------------------
__global__ __launch_bounds__(256) void combine_kernel(const float* __restrict__ x,
                                                      const float* __restrict__ e,
                                                      const float* __restrict__ P,
                                                      const float* __restrict__ cm,
                                                      const float* __restrict__ cs,
                                                      float* __restrict__ out) {
    const int b = blockIdx.x / NSEG;
    const int s = blockIdx.x % NSEG;
    const int tid = threadIdx.x;
    const int wv = tid >> 6, ln = tid & 63;

    // ---- gmax + Z from chunk stats (per-wave, registers only) ----
    const float cmv = cm[b * NC + ln];
    const float csv = cs[b * NC + ln];
    float g = cmv;
    #pragma unroll
    for (int off = 32; off; off >>= 1) g = fmaxf(g, __shfl_xor(g, off));
    float zz = csv * __expf(cmv - g);
    #pragma unroll
    for (int off = 32; off; off >>= 1) zz += __shfl_xor(zz, off);

    // ---- load the batch's 4096 keys, 16/thread via float4 ----
    const float4* eb4 = (const float4*)(e + (size_t)b * TT);
    unsigned key[16];
    #pragma unroll
    for (int j = 0; j < 4; j++) {
        const float4 v = eb4[tid + 256 * j];
        key[4 * j + 0] = flip_key(v.x);
        key[4 * j + 1] = flip_key(v.y);
        key[4 * j + 2] = flip_key(v.z);
        key[4 * j + 3] = flip_key(v.w);
    }

    // ---- P-combine for this segment's chunks (cm via in-wave shuffle) ----
    float acc = 0.f;
    #pragma unroll
    for (int c = 0; c < CPS; c++) {
        const int cc = s * CPS + c;
        const float mcc = __shfl(cmv, cc);
        acc += P[((size_t)b * NC + cc) * FF + tid] * __expf(mcc - g);
    }

    // ---- e-segment preload + emphasis weight precompute ----
    int t = 0; unsigned ky = 0u; float pv = 0.f;
    if (tid < SEGT) {
        t = s * SEGT + tid;
        const float ev = e[(size_t)b * TT + t];
        ky = flip_key(ev);
        pv = EMPH_HALF * __expf(ev - g);
    }

    __shared__ int sc[2][4];
    __shared__ int scount;
    __shared__ int slist[SEGT];
    __shared__ float sval[SEGT];
    if (tid == 0) scount = 0;

    // ---- MSB-first radix select (ballot counting), 1 barrier/round ----
    unsigned prefix = 0u, mask = 0u;
    int kk = K_TOP, ncand = TT;
    int pb = 0;
    for (int bit = 31; bit >= 0; bit--) {
        const unsigned bm = 1u << bit;
        const unsigned m2 = mask | bm;
        const unsigned want = prefix | bm;
        int cnt = 0;
        #pragma unroll
        for (int j = 0; j < 16; j++)
            cnt += (int)__popcll(__ballot((key[j] & m2) == want));
        if (ln == 0) sc[pb][wv] = cnt;
        __syncthreads();
        const int tot = sc[pb][0] + sc[pb][1] + sc[pb][2] + sc[pb][3];
        pb ^= 1;
        if (tot >= kk) {
            prefix = want;
            if (tot == kk) break;    // candidates == k: zero-padded prefix exact
            ncand = tot;
        } else {
            kk -= tot;
            ncand -= tot;
            if (ncand == kk) break;  // all remaining candidates are top-k
        }
        mask = m2;
    }
    const unsigned Kkey = prefix;    // block-uniform

    // ---- build this segment's top-k list in LDS ----
    if (tid < SEGT && ky >= Kkey) {
        const int i = atomicAdd(&scount, 1);
        slist[i] = t;
        sval[i] = pv;
    }
    __syncthreads();

    // ---- gather: ~13 rows/segment, 4-wide unrolled for MLP ----
    const int n = scount;
    const float* xb = x + (size_t)b * TT * FF;
    int i = 0;
    for (; i + 4 <= n; i += 4) {
        const float* p0 = xb + (size_t)slist[i + 0] * FF;
        const float* p1 = xb + (size_t)slist[i + 1] * FF;
        const float* p2 = xb + (size_t)slist[i + 2] * FF;
        const float* p3 = xb + (size_t)slist[i + 3] * FF;
        const float w0 = sval[i + 0], w1 = sval[i + 1];
        const float w2 = sval[i + 2], w3 = sval[i + 3];
        acc += w0 * p0[tid] + w1 * p1[tid] + w2 * p2[tid] + w3 * p3[tid];
    }
    for (; i < n; i++)
        acc += sval[i] * xb[(size_t)slist[i] * FF + tid];

    atomicAdd(&out[b * FF + tid], acc * (1.f / zz));
}

// ---------------------------------------------------------------------------
extern "C" void kernel_launch(void* const* d_in, const int* in_sizes, int n_in,
                              void* d_out, int out_size, void* d_ws, size_t ws_size,
                              hipStream_t stream) {
    const float* x    = (const float*)d_in[0];   // [B,T,F]
    const float* W    = (const float*)d_in[1];   // [F,1]
    const float* bias = (const float*)d_in[2];   // [1]
    float* out = (float*)d_out;                  // [B,1,F]

    float* e     = (float*)d_ws;                 // B*T
    float* P     = e + (size_t)BB * TT;          // B*NC*F
    float* cm    = P + (size_t)BB * NC * FF;     // B*NC
    float* cs    = cm + BB * NC;                 // B*NC

    fused_pass1<<<BB * NC, 256, 0, stream>>>(x, W, bias, e, P, cm, cs, out);
    combine_kernel<<<BB * NSEG, 256, 0, stream>>>(x, e, P, cm, cs, out);
}

// Round 4
// 207.229 us; speedup vs baseline: 1.0901x; 1.0154x over previous
//
#include <hip/hip_runtime.h>
#include <math.h>

#define BB 32
#define TT 4096
#define FF 256
#define CH 64              // timesteps per chunk
#define NC (TT / CH)       // 64 chunks per batch
#define NCB 2              // chunks per pass1 block
#define K_TOP 409          // int(4096 * 0.1)
#define EMPH_HALF 0.5f     // (1.5 - 1.0)
#define NSEG 32            // combine segments per batch (128 timesteps each)
#define SEGT (TT / NSEG)   // 128
#define CPS (NC / NSEG)    // 2 chunks per segment

__device__ __forceinline__ unsigned flip_key(float v) {
    unsigned u = __float_as_uint(v);
    return (u & 0x80000000u) ? ~u : (u | 0x80000000u);
}
// fast tanh: (e^{2z}-1)/(e^{2z}+1), clamped so e^{2z} never overflows
__device__ __forceinline__ float fast_tanh(float z) {
    z = fminf(fmaxf(z, -15.f), 15.f);
    const float t = __expf(2.f * z);
    return (t - 1.f) * __builtin_amdgcn_rcpf(t + 1.f);
}

// ---------------------------------------------------------------------------
// K1: fused scores + online-softmax chunk partials. ONE HBM pass over x.
// grid = B*NC/NCB = 1024 blocks of 256 (4 waves). __launch_bounds__(256,4)
// => 4 blocks/CU x 256 CU = 1024: ALL blocks co-resident, exactly one
// scheduling round (no straggler partial round). Each block processes NCB=2
// consecutive chunks; per chunk, each wave owns 4 rows per 16-row sub-tile
// with a PRIVATE online-softmax state; 4 wave-partials merge once per chunk.
// Outputs: e[B*T], P[B*NC*F] = sum_t exp(e-m_c) x, cm[B*NC], cs[B*NC].
// Also zeros out[b,:] (first block of each batch) for K3's atomics.
// ---------------------------------------------------------------------------
__global__ __launch_bounds__(256, 4) void fused_pass1(const float* __restrict__ x,
                                                      const float* __restrict__ W,
                                                      const float* __restrict__ bias,
                                                      float* __restrict__ e,
                                                      float* __restrict__ P,
                                                      float* __restrict__ cm,
                                                      float* __restrict__ cs,
                                                      float* __restrict__ out) {
    const int chunk0 = blockIdx.x * NCB;
    const int b  = chunk0 / NC;
    const int cb = chunk0 % NC;              // first chunk within batch
    const int tid = threadIdx.x;
    const int wv = tid >> 6, ln = tid & 63;

    if (cb == 0) out[b * FF + tid] = 0.f;    // zero for K3's atomicAdd

    const float4 wvec = ((const float4*)W)[ln];
    const float  bb   = bias[0];

    __shared__ float4 part4[4][64];
    __shared__ float sm[4], ss4[4];

    #pragma unroll
    for (int u = 0; u < NCB; u++) {
        const int c = cb + u;
        const float* xc = x + ((size_t)b * TT + (size_t)c * CH) * FF;

        float4 acc = make_float4(0.f, 0.f, 0.f, 0.f);
        float  m = -1e30f, ssum = 0.f;

        #pragma unroll
        for (int s0 = 0; s0 < CH; s0 += 16) {
            const int r0 = s0 + wv * 4;         // this wave's 4 rows
            float4 xr[4];
            #pragma unroll
            for (int i = 0; i < 4; i++)
                xr[i] = ((const float4*)(xc + (size_t)(r0 + i) * FF))[ln];

            float dv[4];
            #pragma unroll
            for (int i = 0; i < 4; i++)
                dv[i] = xr[i].x * wvec.x + xr[i].y * wvec.y +
                        xr[i].z * wvec.z + xr[i].w * wvec.w;
            #pragma unroll
            for (int i = 0; i < 4; i++) {
                float d = dv[i];
                #pragma unroll
                for (int off = 32; off; off >>= 1) d += __shfl_xor(d, off);
                dv[i] = fast_tanh(d + bb);      // all 64 lanes hold the score
            }
            if (ln == 0)
                *(float4*)(e + (size_t)b * TT + c * CH + r0) =
                    make_float4(dv[0], dv[1], dv[2], dv[3]);

            // private online-softmax update (registers only, no sync)
            float lm = m;
            #pragma unroll
            for (int i = 0; i < 4; i++) lm = fmaxf(lm, dv[i]);
            const float alpha = __expf(m - lm);
            acc.x *= alpha; acc.y *= alpha; acc.z *= alpha; acc.w *= alpha;
            ssum *= alpha;
            #pragma unroll
            for (int i = 0; i < 4; i++) {
                const float wgt = __expf(dv[i] - lm);
                ssum += wgt;
                acc.x += wgt * xr[i].x; acc.y += wgt * xr[i].y;
                acc.z += wgt * xr[i].z; acc.w += wgt * xr[i].w;
            }
            m = lm;
        }

        // ---- merge the 4 per-wave partials (one sync in, one sync out) ----
        part4[wv][ln] = acc;
        if (ln == 0) { sm[wv] = m; ss4[wv] = ssum; }
        __syncthreads();

        const float m0 = sm[0], m1 = sm[1], m2 = sm[2], m3 = sm[3];
        const float mc = fmaxf(fmaxf(m0, m1), fmaxf(m2, m3));
        const float s0s = __expf(m0 - mc), s1s = __expf(m1 - mc);
        const float s2s = __expf(m2 - mc), s3s = __expf(m3 - mc);
        const float* pf = (const float*)part4;  // [4][256] floats
        const float p = pf[tid] * s0s + pf[256 + tid] * s1s +
                        pf[512 + tid] * s2s + pf[768 + tid] * s3s;
        P[((size_t)b * NC + c) * FF + tid] = p;
        if (tid == 0) {
            cm[b * NC + c] = mc;
            cs[b * NC + c] = ss4[0] * s0s + ss4[1] * s1s + ss4[2] * s2s + ss4[3] * s3s;
        }
        __syncthreads();                        // LDS reused by next chunk
    }
}

// ---------------------------------------------------------------------------
// K2: per-batch stats, one block per batch. gmax/Z from chunk (m,s);
// ballot-based radix select of the K_TOP-th largest score key.
// Single barrier per round (double-buffered cross-wave counts) + early exit
// when candidate count == remaining k (prefix zero-padded is then exact).
// stats[b] = {gmax, Z, Kkey-bits}.
// ---------------------------------------------------------------------------
__global__ __launch_bounds__(256) void select_kernel(const float* __restrict__ e,
                                                     const float* __restrict__ cm,
                                                     const float* __restrict__ cs,
                                                     float* __restrict__ stats) {
    const int b = blockIdx.x;
    const int tid = threadIdx.x;
    const int wv = tid >> 6, ln = tid & 63;

    // ---- gmax + Z over NC=64 chunks (wave 0, registers only) ----
    float g = 0.f, zz = 0.f;
    if (tid < 64) {
        const float mm = cm[b * NC + tid];
        const float ss = cs[b * NC + tid];
        g = mm;
        #pragma unroll
        for (int off = 32; off; off >>= 1) g = fmaxf(g, __shfl_xor(g, off));
        zz = ss * __expf(mm - g);
        #pragma unroll
        for (int off = 32; off; off >>= 1) zz += __shfl_xor(zz, off);
    }

    // ---- load 16 keys/thread via float4 (coalesced 16B/lane) ----
    const float4* eb4 = (const float4*)(e + (size_t)b * TT);
    unsigned key[16];
    #pragma unroll
    for (int j = 0; j < 4; j++) {
        const float4 v = eb4[tid + 256 * j];
        key[4 * j + 0] = flip_key(v.x);
        key[4 * j + 1] = flip_key(v.y);
        key[4 * j + 2] = flip_key(v.z);
        key[4 * j + 3] = flip_key(v.w);
    }

    // ---- MSB-first radix select (ballot counting), 1 barrier/round ----
    __shared__ int sc[2][4];
    unsigned prefix = 0u, mask = 0u;
    int kk = K_TOP;
    int pb = 0;
    for (int bit = 31; bit >= 0; bit--) {
        const unsigned bm = 1u << bit;
        const unsigned m2 = mask | bm;
        const unsigned want = prefix | bm;
        int cnt = 0;
        #pragma unroll
        for (int j = 0; j < 16; j++)
            cnt += (int)__popcll(__ballot((key[j] & m2) == want));
        if (ln == 0) sc[pb][wv] = cnt;
        __syncthreads();
        const int tot = sc[pb][0] + sc[pb][1] + sc[pb][2] + sc[pb][3];
        pb ^= 1;
        if (tot >= kk) {
            prefix = want;
            if (tot == kk) break;    // candidates == k: zero-padded prefix is exact
        } else {
            kk -= tot;
        }
        mask = m2;
    }

    if (tid == 0) {
        stats[3 * b + 0] = g;
        stats[3 * b + 1] = zz;
        stats[3 * b + 2] = __uint_as_float(prefix);
    }
}

// ---------------------------------------------------------------------------
// K3: parallel combine + top-k emphasis gather.
// grid = B*NSEG = 1024 blocks of 256 (4 blocks/CU); block (b,s) handles
// chunks 2s..2s+1 and timesteps [s*128, (s+1)*128). Thread tid owns feature
// tid. Gather is 4-wide unrolled so 4 independent loads are in flight.
// out[b,f] += ( sum_c P*e^{m_c-gmax} + 0.5*sum_{topk t} e^{e_t-gmax} x ) / Z
// ---------------------------------------------------------------------------
__global__ __launch_bounds__(256) void combine_kernel(const float* __restrict__ x,
                                                      const float* __restrict__ e,
                                                      const float* __restrict__ P,
                                                      const float* __restrict__ cm,
                                                      const float* __restrict__ stats,
                                                      float* __restrict__ out) {
    const int b = blockIdx.x / NSEG;
    const int s = blockIdx.x % NSEG;
    const int tid = threadIdx.x;

    const float gmax = stats[3 * b + 0];
    const float Z    = stats[3 * b + 1];
    const unsigned Kkey = __float_as_uint(stats[3 * b + 2]);

    float acc = 0.f;
    #pragma unroll
    for (int c = 0; c < CPS; c++) {
        const int cc = s * CPS + c;
        const float sc2 = __expf(cm[b * NC + cc] - gmax);
        acc += P[((size_t)b * NC + cc) * FF + tid] * sc2;
    }

    __shared__ int scount;
    __shared__ int slist[SEGT];
    __shared__ float sval[SEGT];
    if (tid == 0) scount = 0;
    __syncthreads();

    if (tid < SEGT) {
        const int t = s * SEGT + tid;
        const float ev = e[(size_t)b * TT + t];
        if (flip_key(ev) >= Kkey) {
            const int i = atomicAdd(&scount, 1);
            slist[i] = t;
            sval[i] = EMPH_HALF * __expf(ev - gmax);
        }
    }
    __syncthreads();

    const int n = scount;
    const float* xb = x + (size_t)b * TT * FF;
    int i = 0;
    for (; i + 4 <= n; i += 4) {
        const float* p0 = xb + (size_t)slist[i + 0] * FF;
        const float* p1 = xb + (size_t)slist[i + 1] * FF;
        const float* p2 = xb + (size_t)slist[i + 2] * FF;
        const float* p3 = xb + (size_t)slist[i + 3] * FF;
        const float w0 = sval[i + 0], w1 = sval[i + 1];
        const float w2 = sval[i + 2], w3 = sval[i + 3];
        acc += w0 * p0[tid] + w1 * p1[tid] + w2 * p2[tid] + w3 * p3[tid];
    }
    for (; i < n; i++)
        acc += sval[i] * xb[(size_t)slist[i] * FF + tid];

    atomicAdd(&out[b * FF + tid], acc * (1.f / Z));
}

// ---------------------------------------------------------------------------
extern "C" void kernel_launch(void* const* d_in, const int* in_sizes, int n_in,
                              void* d_out, int out_size, void* d_ws, size_t ws_size,
                              hipStream_t stream) {
    const float* x    = (const float*)d_in[0];   // [B,T,F]
    const float* W    = (const float*)d_in[1];   // [F,1]
    const float* bias = (const float*)d_in[2];   // [1]
    float* out = (float*)d_out;                  // [B,1,F]

    float* e     = (float*)d_ws;                 // B*T
    float* P     = e + (size_t)BB * TT;          // B*NC*F
    float* cm    = P + (size_t)BB * NC * FF;     // B*NC
    float* cs    = cm + BB * NC;                 // B*NC
    float* stats = cs + BB * NC;                 // 3*B

    fused_pass1<<<BB * NC / NCB, 256, 0, stream>>>(x, W, bias, e, P, cm, cs, out);
    select_kernel<<<BB, 256, 0, stream>>>(e, cm, cs, stats);
    combine_kernel<<<BB * NSEG, 256, 0, stream>>>(x, e, P, cm, stats, out);
}